// Round 9
// baseline (23221.809 us; speedup 1.0000x reference)
//
#include <hip/hip_runtime.h>

#define NN 4096
#define NSTEPS 100
#define TPB 1024
#define NBLK 64      // cost model: staging B/47 + compute 110/B + 1.0 us/step
#define CSTRIDE 16   // 64B padding for counters / gen words

// Coherent (cross-XCD) 8-byte ops: relaxed agent-scope atomics compile to
// sc-flagged global ops that bypass non-coherent L1/L2 and hit the coherence
// point directly — with NO wbl2/inv cache maintenance (R1 killer) and no
// cache-inv correctness gamble (R7 killer).
__device__ __forceinline__ void zstore(float2* p, float2 v) {
    union { float2 f; unsigned long long u; } c; c.f = v;
    __hip_atomic_store((unsigned long long*)p, c.u, __ATOMIC_RELAXED,
                       __HIP_MEMORY_SCOPE_AGENT);
}
__device__ __forceinline__ unsigned long long zload_u64(const float2* p) {
    return __hip_atomic_load((const unsigned long long*)p, __ATOMIC_RELAXED,
                             __HIP_MEMORY_SCOPE_AGENT);
}

// Persistent kernel, R8 reshape: 64 blocks x 1024 threads. Block owns 64 rows;
// wave w owns rows bid*64+4w..+3 FULL-width (no cross-wave combine). K = 4x16
// float4 = 256 VGPRs/thread, asm-pinned. z_g (g>=1) lives in zb[g&1].
// Staging: uncached u64 loads (proven R4/R5). Barrier: R4 3-hop (proven),
// with all-wave store-drain + __syncthreads before arrival since all 16
// waves publish rows.
__global__ __launch_bounds__(TPB) void k_persist(
    const float* __restrict__ K, const float2* __restrict__ z0,
    float2* __restrict__ zb0, float2* __restrict__ zb1,
    float2* __restrict__ zfinal, const float* __restrict__ omega_p,
    const float* __restrict__ dt_p, int* flags) {
    __shared__ float zr[NN];
    __shared__ float zi[NN];
    __shared__ int lbar;

    const int tid  = threadIdx.x;
    const int bid  = blockIdx.x;
    const int w    = tid >> 6, lane = tid & 63;
    const int rb   = bid * 64 + w * 4;          // wave's 4 rows, full width
    const int la4  = lane * 4;                  // col base; j stride 256

    int* agg = flags;                 // 4 arrival counters (64B apart)
    int* gen = flags + 16 * CSTRIDE;  // 8 generation words (64B apart)

    const float omega = *omega_p;
    const float dt    = *dt_p;
    const float inv2n = 1.0f / (2.0f * NN);

    if (tid == 0) lbar = 0;

    // ---- K fragment: 4 rows x 16 float4 = 256 VGPRs ----
    float4 kA[4][16];
#pragma unroll
    for (int r = 0; r < 4; ++r) {
        const float* Kr = K + (size_t)(rb + r) * NN + la4;
#pragma unroll
        for (int j = 0; j < 16; ++j) kA[r][j] = *(const float4*)(Kr + j * 256);
    }

    for (int s = 0; s < NSTEPS; ++s) {
        // Pin kA in registers: opaque redefinition each iteration so the
        // compiler can neither spill-and-reload nor refold the global loads.
#pragma unroll
        for (int r = 0; r < 4; ++r)
#pragma unroll
            for (int j = 0; j < 16; ++j)
                asm volatile("" : "+v"(kA[r][j].x), "+v"(kA[r][j].y),
                                  "+v"(kA[r][j].z), "+v"(kA[r][j].w));

        // ---- stage z_s -> LDS (SoA), 4 elements/thread, stride-1 ----
        if (s == 0) {
#pragma unroll
            for (int it = 0; it < 4; ++it) {
                int idx = it * TPB + tid;
                float2 v = z0[idx];
                zr[idx] = v.x; zi[idx] = v.y;
            }
        } else {
            const float2* zsrc = (s & 1) ? zb1 : zb0;   // z_s in zb[s&1]
#pragma unroll
            for (int it = 0; it < 4; ++it) {
                int idx = it * TPB + tid;
                unsigned long long u = zload_u64(zsrc + idx);
                union { unsigned u; float f; } cx, cy;
                cx.u = (unsigned)u;
                cy.u = (unsigned)(u >> 32);
                zr[idx] = cx.f; zi[idx] = cy.f;
            }
        }
        __syncthreads();

        // ---- dots: 4 rows x 4096 cols per wave, K from regs, z from LDS ----
        float sr0 = 0, sr1 = 0, sr2 = 0, sr3 = 0;
        float si0 = 0, si1 = 0, si2 = 0, si3 = 0;
#pragma unroll
        for (int j = 0; j < 16; ++j) {
            float4 a = *(const float4*)&zr[j * 256 + la4];
            float4 b = *(const float4*)&zi[j * 256 + la4];
            float4 k0 = kA[0][j], k1 = kA[1][j], k2 = kA[2][j], k3 = kA[3][j];
            sr0 += k0.x * a.x + k0.y * a.y + k0.z * a.z + k0.w * a.w;
            si0 += k0.x * b.x + k0.y * b.y + k0.z * b.z + k0.w * b.w;
            sr1 += k1.x * a.x + k1.y * a.y + k1.z * a.z + k1.w * a.w;
            si1 += k1.x * b.x + k1.y * b.y + k1.z * b.z + k1.w * b.w;
            sr2 += k2.x * a.x + k2.y * a.y + k2.z * a.z + k2.w * a.w;
            si2 += k2.x * b.x + k2.y * b.y + k2.z * b.z + k2.w * b.w;
            sr3 += k3.x * a.x + k3.y * a.y + k3.z * a.z + k3.w * a.w;
            si3 += k3.x * b.x + k3.y * b.y + k3.z * b.z + k3.w * b.w;
        }
#pragma unroll
        for (int off = 32; off; off >>= 1) {
            sr0 += __shfl_xor(sr0, off, 64); si0 += __shfl_xor(si0, off, 64);
            sr1 += __shfl_xor(sr1, off, 64); si1 += __shfl_xor(si1, off, 64);
            sr2 += __shfl_xor(sr2, off, 64); si2 += __shfl_xor(si2, off, 64);
            sr3 += __shfl_xor(sr3, off, 64); si3 += __shfl_xor(si3, off, 64);
        }

        // ---- lanes 0..3 of each wave: ODE update for rows rb..rb+3 ----
        float2* zo = (s == NSTEPS - 1) ? zfinal
                                       : (((s + 1) & 1) ? zb1 : zb0);
        if (lane < 4) {
            float u  = lane == 0 ? sr0 : lane == 1 ? sr1 : lane == 2 ? sr2 : sr3;
            float vv = lane == 0 ? si0 : lane == 1 ? si1 : lane == 2 ? si2 : si3;
            const int row = rb + lane;
            float x = zr[row], y = zi[row];
            float A = x * x - y * y;           // Re(z^2)
            float B = 2.0f * x * y;            // Im(z^2)
            float dzr = inv2n * (u - (u * A + vv * B)) + omega * x;
            float dzi = inv2n * (vv - (u * B - vv * A)) + omega * y;
            float nx = x + dt * dzr;
            float ny = y + dt * dzi;
            float a2 = nx * nx + ny * ny;
            if (a2 >= 0.999f * 0.999f) {
                float sc = 0.999f / sqrtf(a2);
                nx *= sc; ny *= sc;
            }
            if (s == NSTEPS - 1) zfinal[row] = make_float2(nx, ny);
            else                 zstore(zo + row, make_float2(nx, ny));
        }

        // ---- barrier (R4 3-hop; skip after last step) ----
        if (s != NSTEPS - 1) {
            const int target = s + 1;
            __builtin_amdgcn_s_waitcnt(0);   // every wave drains its publish
            __syncthreads();                 // all 16 waves' stores ack'd
            if (w == 0) {
                if (lane == 0)
                    __hip_atomic_fetch_add(&agg[(bid >> 4) * CSTRIDE], 1,
                                           __ATOMIC_RELAXED,
                                           __HIP_MEMORY_SCOPE_AGENT);
                if (bid == 0) {
                    const int need = 16 * target;   // 4 counters x 16 blocks
                    for (;;) {
                        int c = (lane < 4)
                            ? __hip_atomic_load(&agg[lane * CSTRIDE],
                                                __ATOMIC_RELAXED,
                                                __HIP_MEMORY_SCOPE_AGENT)
                            : need;
                        if (__all(c >= need)) break;
                        __builtin_amdgcn_s_sleep(1);
                    }
                    __atomic_signal_fence(__ATOMIC_SEQ_CST);
                    if (lane < 8)
                        __hip_atomic_store(&gen[lane * CSTRIDE], target,
                                           __ATOMIC_RELAXED,
                                           __HIP_MEMORY_SCOPE_AGENT);
                } else {
                    if (lane == 0) {
                        while (__hip_atomic_load(&gen[(bid >> 3) * CSTRIDE],
                                                 __ATOMIC_RELAXED,
                                                 __HIP_MEMORY_SCOPE_AGENT) < target)
                            __builtin_amdgcn_s_sleep(1);
                    }
                }
                __atomic_signal_fence(__ATOMIC_SEQ_CST);
                if (lane == 0) *(volatile int*)&lbar = target;
            } else {
                while (*(volatile int*)&lbar < target) __builtin_amdgcn_s_sleep(1);
                __atomic_signal_fence(__ATOMIC_SEQ_CST);
            }
        }
    }
}

// ---- generic fallback: per-step launches ----
__global__ __launch_bounds__(256) void k_step_f32(
    const float* __restrict__ K, const float2* __restrict__ zin,
    float2* __restrict__ zout, const float* __restrict__ omega_p,
    const float* __restrict__ dt_p, int n) {
    const int wave = threadIdx.x >> 6;
    const int lane = threadIdx.x & 63;
    const int row  = blockIdx.x * 4 + wave;
    if (row >= n) return;
    float sr = 0.0f, si = 0.0f;
    for (int c = lane; c < n; c += 64) {
        float k = K[(size_t)row * n + c];
        float2 z = zin[c];
        sr += k * z.x;
        si += k * z.y;
    }
#pragma unroll
    for (int off = 32; off; off >>= 1) {
        sr += __shfl_down(sr, off, 64);
        si += __shfl_down(si, off, 64);
    }
    if (lane == 0) {
        float u = sr, v = si;
        float2 zc = zin[row];
        float x = zc.x, y = zc.y;
        float inv2n = 1.0f / (2.0f * n);
        float A = x * x - y * y, B = 2.0f * x * y;
        float dzr = inv2n * (u - (u * A + v * B)) + (*omega_p) * x;
        float dzi = inv2n * (v - (u * B - v * A)) + (*omega_p) * y;
        float nx = x + (*dt_p) * dzr, ny = y + (*dt_p) * dzi;
        float a2 = nx * nx + ny * ny;
        if (a2 >= 0.999f * 0.999f) { float sc = 0.999f / sqrtf(a2); nx *= sc; ny *= sc; }
        zout[row] = make_float2(nx, ny);
    }
}

extern "C" void kernel_launch(void* const* d_in, const int* in_sizes, int n_in,
                              void* d_out, int out_size, void* d_ws, size_t ws_size,
                              hipStream_t stream) {
    const float2* z0      = (const float2*)d_in[0];
    const float*  K       = (const float*)d_in[1];
    const float*  omega_p = (const float*)d_in[2];
    const float*  dt_p    = (const float*)d_in[3];
    const int n = in_sizes[0] / 2;
    float2* out = (float2*)d_out;

    const size_t flags_bytes = 4096;  // 4 counters + 8 gen words, 64B-padded
    const size_t need = flags_bytes + 2 * (size_t)NN * sizeof(float2);
    if (n == NN && ws_size >= need) {
        int*    flags = (int*)d_ws;
        float2* zb0   = (float2*)((char*)d_ws + flags_bytes);
        float2* zb1   = zb0 + NN;
        hipMemsetAsync(d_ws, 0, flags_bytes, stream);
        k_persist<<<NBLK, TPB, 0, stream>>>(K, z0, zb0, zb1, out,
                                            omega_p, dt_p, flags);
    } else {
        float2* zb0 = (float2*)d_ws;
        float2* zb1 = zb0 + n;
        const float2* cur = z0;
        for (int s = 0; s < NSTEPS; ++s) {
            float2* nxt = (s == NSTEPS - 1) ? out : ((s & 1) ? zb1 : zb0);
            k_step_f32<<<(n + 3) / 4, 256, 0, stream>>>(K, cur, nxt, omega_p, dt_p, n);
            cur = nxt;
        }
    }
}

// Round 10
// 803.121 us; speedup vs baseline: 28.9144x; 28.9144x over previous
//
#include <hip/hip_runtime.h>

#define NN 4096
#define NSTEPS 100
#define TPB 512
#define NBLK 256     // unique full-K-residency shape: 256 blk x 512 thr x 128 VGPR

// Relaxed agent-scope atomics: sc-flagged global ops straight to the
// coherence point; no L1/L2 involvement, no wbl2/inv cache maintenance.
__device__ __forceinline__ void dstore_u32(unsigned* p, unsigned v) {
    __hip_atomic_store(p, v, __ATOMIC_RELAXED, __HIP_MEMORY_SCOPE_AGENT);
}
__device__ __forceinline__ unsigned dload_u32(const unsigned* p) {
    return __hip_atomic_load(p, __ATOMIC_RELAXED, __HIP_MEMORY_SCOPE_AGENT);
}
__device__ __forceinline__ unsigned short f_to_bf16_rne(float f) {
    union { float f; unsigned i; } c; c.f = f;
    unsigned u = c.i;
    u += 0x7fffu + ((u >> 16) & 1u);     // round-to-nearest-even
    return (unsigned short)(u >> 16);
}

// Barrier-free persistent kernel with DELTA exchange.
// Invariant: all blocks hold identical fp32 z_s in LDS (zr/zi), reconstructed
// from the identical Δ stream (z_{s+1} = z_s + decode(Δ'_{s+1})) — so only
// 4 B/oscillator crosses the fabric per step (half the R4/R5 line traffic).
// Δ word: [bf16(Δx)<<16 | bf16(Δy)]; 2-bit tag (s&3) in the two bf16 LSBs.
// Parity buffers db0/db1 ⇒ stale tag differs by 2 (mod 4); 0-fill/0xAA ⇒ tag
// 0 ≠ first tags 1,2. Tag-gate + one __syncthreads/step: a wave reaches sync
// #(s+1) only after every block-mate published s+1 (passed sync #(s)) — no
// barrier aliasing (the R6 bug), no LDS read/write races.
__global__ __launch_bounds__(TPB, 2) void k_persist(
    const float* __restrict__ K, const float2* __restrict__ z0,
    unsigned* __restrict__ db0, unsigned* __restrict__ db1,
    float2* __restrict__ zfinal, const float* __restrict__ omega_p,
    const float* __restrict__ dt_p) {
    __shared__ float zr[NN];
    __shared__ float zi[NN];

    const int tid  = threadIdx.x;
    const int bid  = blockIdx.x;
    const int w    = tid >> 6, lane = tid & 63;
    const int rb   = bid * 16 + w * 2;   // wave's 2 rows, full width
    const int la4  = lane * 4;           // col base; j stride 256
    const int rot  = bid & 7;            // spread staging demand

    const float omega = *omega_p;
    const float dt    = *dt_p;
    const float inv2n = 1.0f / (2.0f * NN);

    // ---- K fragment: 2 rows x 16 float4 = 128 VGPRs ----
    float4 kA[2][16];
#pragma unroll
    for (int r = 0; r < 2; ++r) {
        const float* Kr = K + (size_t)(rb + r) * NN + la4;
#pragma unroll
        for (int j = 0; j < 16; ++j) kA[r][j] = *(const float4*)(Kr + j * 256);
    }

    for (int s = 0; s < NSTEPS; ++s) {
        // Pin kA in registers (opaque redefinition: no refold/spill).
#pragma unroll
        for (int r = 0; r < 2; ++r)
#pragma unroll
            for (int j = 0; j < 16; ++j)
                asm volatile("" : "+v"(kA[r][j].x), "+v"(kA[r][j].y),
                                  "+v"(kA[r][j].z), "+v"(kA[r][j].w));

        // ---- stage/reconstruct z_s in LDS ----
        if (s == 0) {
#pragma unroll
            for (int it = 0; it < 8; ++it) {
                int idx = it * TPB + tid;
                float2 v = z0[idx];
                zr[idx] = v.x; zi[idx] = v.y;
            }
        } else {
            const unsigned* dsrc = (s & 1) ? db1 : db0;   // Δ for z_s
            const unsigned tag = (unsigned)(s & 3);
            unsigned vv[8];
            int ofs[8];
#pragma unroll
            for (int it = 0; it < 8; ++it) {              // all 8 in flight
                ofs[it] = ((it + rot) & 7) * TPB + tid;
                vv[it] = dload_u32(dsrc + ofs[it]);
            }
#pragma unroll
            for (int it = 0; it < 8; ++it) {              // retry only stale
                while ((((vv[it] >> 16) & 1u) * 2u + (vv[it] & 1u)) != tag) {
                    __builtin_amdgcn_s_sleep(1);
                    vv[it] = dload_u32(dsrc + ofs[it]);
                }
            }
#pragma unroll
            for (int it = 0; it < 8; ++it) {              // z += decode(Δ')
                union { unsigned u; float f; } fx, fy;
                fx.u = vv[it] & 0xFFFF0000u;
                fy.u = vv[it] << 16;
                zr[ofs[it]] += fx.f;
                zi[ofs[it]] += fy.f;
            }
        }
        __syncthreads();

        // ---- dots: 2 rows x 4096 cols per wave, K from regs, z from LDS ----
        float sr0 = 0, si0 = 0, sr1 = 0, si1 = 0;
#pragma unroll
        for (int j = 0; j < 16; ++j) {
            const float4 a = *(const float4*)&zr[j * 256 + la4];
            const float4 b = *(const float4*)&zi[j * 256 + la4];
            const float4 k0 = kA[0][j], k1 = kA[1][j];
            sr0 += k0.x * a.x + k0.y * a.y + k0.z * a.z + k0.w * a.w;
            si0 += k0.x * b.x + k0.y * b.y + k0.z * b.z + k0.w * b.w;
            sr1 += k1.x * a.x + k1.y * a.y + k1.z * a.z + k1.w * a.w;
            si1 += k1.x * b.x + k1.y * b.y + k1.z * b.z + k1.w * b.w;
        }
#pragma unroll
        for (int off = 32; off; off >>= 1) {
            sr0 += __shfl_xor(sr0, off, 64); si0 += __shfl_xor(si0, off, 64);
            sr1 += __shfl_xor(sr1, off, 64); si1 += __shfl_xor(si1, off, 64);
        }

        // ---- lanes 0,1: ODE update for rows rb, rb+1 + publish Δ ----
        if (lane < 2) {
            const float u  = lane ? sr1 : sr0;   // Re(K z)
            const float vv = lane ? si1 : si0;   // Im(K z)
            const int row = rb + lane;
            float x = zr[row], y = zi[row];
            float A = x * x - y * y;             // Re(z^2)
            float B = 2.0f * x * y;              // Im(z^2)
            float dzr = inv2n * (u - (u * A + vv * B)) + omega * x;
            float dzi = inv2n * (vv - (u * B - vv * A)) + omega * y;
            float nx = x + dt * dzr;
            float ny = y + dt * dzi;
            float a2 = nx * nx + ny * ny;
            if (a2 >= 0.999f * 0.999f) {
                float sc = 0.999f / sqrtf(a2);
                nx *= sc; ny *= sc;
            }
            if (s == NSTEPS - 1) {
                zfinal[row] = make_float2(nx, ny);
            } else {
                const unsigned t = (unsigned)((s + 1) & 3);
                unsigned ux = f_to_bf16_rne(nx - x);
                unsigned uy = f_to_bf16_rne(ny - y);
                ux = (ux & ~1u) | ((t >> 1) & 1u);
                uy = (uy & ~1u) | (t & 1u);
                unsigned* ddst = ((s + 1) & 1) ? db1 : db0;
                dstore_u32(ddst + row, (ux << 16) | uy);   // fire-and-forget
            }
        }
        // no end-of-step barrier — tag gate orders everything
    }
}

// ---- generic fallback: per-step launches ----
__global__ __launch_bounds__(256) void k_step_f32(
    const float* __restrict__ K, const float2* __restrict__ zin,
    float2* __restrict__ zout, const float* __restrict__ omega_p,
    const float* __restrict__ dt_p, int n) {
    const int wave = threadIdx.x >> 6;
    const int lane = threadIdx.x & 63;
    const int row  = blockIdx.x * 4 + wave;
    if (row >= n) return;
    float sr = 0.0f, si = 0.0f;
    for (int c = lane; c < n; c += 64) {
        float k = K[(size_t)row * n + c];
        float2 z = zin[c];
        sr += k * z.x;
        si += k * z.y;
    }
#pragma unroll
    for (int off = 32; off; off >>= 1) {
        sr += __shfl_down(sr, off, 64);
        si += __shfl_down(si, off, 64);
    }
    if (lane == 0) {
        float u = sr, v = si;
        float2 zc = zin[row];
        float x = zc.x, y = zc.y;
        float inv2n = 1.0f / (2.0f * n);
        float A = x * x - y * y, B = 2.0f * x * y;
        float dzr = inv2n * (u - (u * A + v * B)) + (*omega_p) * x;
        float dzi = inv2n * (v - (u * B - v * A)) + (*omega_p) * y;
        float nx = x + (*dt_p) * dzr, ny = y + (*dt_p) * dzi;
        float a2 = nx * nx + ny * ny;
        if (a2 >= 0.999f * 0.999f) { float sc = 0.999f / sqrtf(a2); nx *= sc; ny *= sc; }
        zout[row] = make_float2(nx, ny);
    }
}

extern "C" void kernel_launch(void* const* d_in, const int* in_sizes, int n_in,
                              void* d_out, int out_size, void* d_ws, size_t ws_size,
                              hipStream_t stream) {
    const float2* z0      = (const float2*)d_in[0];
    const float*  K       = (const float*)d_in[1];
    const float*  omega_p = (const float*)d_in[2];
    const float*  dt_p    = (const float*)d_in[3];
    const int n = in_sizes[0] / 2;
    float2* out = (float2*)d_out;

    const size_t dbytes = (size_t)NN * sizeof(unsigned);   // 16 KB per parity
    const size_t need = 2 * dbytes;
    if (n == NN && ws_size >= need) {
        unsigned* db0 = (unsigned*)d_ws;
        unsigned* db1 = db0 + NN;
        hipMemsetAsync(d_ws, 0, need, stream);   // tag 0 != first tags 1,2
        k_persist<<<NBLK, TPB, 0, stream>>>(K, z0, db0, db1, out,
                                            omega_p, dt_p);
    } else {
        float2* zb0 = (float2*)d_ws;
        float2* zb1 = zb0 + n;
        const float2* cur = z0;
        for (int s = 0; s < NSTEPS; ++s) {
            float2* nxt = (s == NSTEPS - 1) ? out : ((s & 1) ? zb1 : zb0);
            k_step_f32<<<(n + 3) / 4, 256, 0, stream>>>(K, cur, nxt, omega_p, dt_p, n);
            cur = nxt;
        }
    }
}